// Round 9
// baseline (876.279 us; speedup 1.0000x reference)
//
#include <hip/hip_runtime.h>
#include <hip/hip_bf16.h>

#define N_NODES 10000
#define N_EDGES 160000

typedef __hip_bfloat16 bf16;
typedef unsigned short u16;
typedef float f32x4 __attribute__((ext_vector_type(4)));
typedef short s16x8 __attribute__((ext_vector_type(8)));
typedef unsigned short us8 __attribute__((ext_vector_type(8)));
typedef unsigned short us4 __attribute__((ext_vector_type(4)));

static __device__ __forceinline__ float b2f(u16 u) {
    unsigned v = (unsigned)u << 16;
    return __uint_as_float(v);
}
static __device__ __forceinline__ u16 f2b(float f) {
    bf16 b = __float2bfloat16(f);
    return *reinterpret_cast<u16*>(&b);
}

// async global->LDS, 16B per lane; LDS dest = wave-uniform base + lane*16
#define GLDS(gp, lp)                                                         \
    __builtin_amdgcn_global_load_lds(                                        \
        (const __attribute__((address_space(1))) void*)(const void*)(gp),    \
        (__attribute__((address_space(3))) void*)(lp), 16, 0, 0)

// ---------------- prep: x conv + edge extract + degree count + W transposes ------
// blocks [0,2500): xb convert + edge extract + deg count. deg pre-zeroed.
// blocks [2500, 2500+1024): transpose WT[n][k] = bf16(W[k][n]).

__global__ void k_prep(const int* __restrict__ ei, const float* __restrict__ x,
                       u16* __restrict__ xb,
                       int* __restrict__ row, int* __restrict__ col,
                       int* __restrict__ deg,
                       const float* __restrict__ W1, const float* __restrict__ W2,
                       const float* __restrict__ W3, const float* __restrict__ W4,
                       u16* __restrict__ T1, u16* __restrict__ T2,
                       u16* __restrict__ T3, u16* __restrict__ T4) {
    __shared__ u16 tile[32][33];
    if (blockIdx.x < 2500) {
        int t = blockIdx.x * 256 + threadIdx.x;  // 0 .. 639999
        float4 v = *(const float4*)(x + (size_t)t * 4);
        us4 st;
        st[0] = f2b(v.x); st[1] = f2b(v.y); st[2] = f2b(v.z); st[3] = f2b(v.w);
        *(us4*)(xb + (size_t)t * 4) = st;

        if (t < N_EDGES) {
            bool is64 = true;
#pragma unroll
            for (int k = 0; k < 8; ++k) is64 = is64 && (ei[2 * k + 1] == 0);
            int r, c;
            if (is64) {
                r = ei[2 * t];
                c = ei[2 * (N_EDGES + t)];
            } else {
                r = ei[t];
                c = ei[N_EDGES + t];
            }
            row[t] = r;
            col[t] = c;
            atomicAdd(&deg[c], 1);
        }
        return;
    }
    int b = blockIdx.x - 2500;        // 0..1023
    int z = b >> 8;                   // 0..3
    int rem = b & 255;
    int by = rem >> 4, bx = rem & 15;
    const float* W = (z == 0) ? W1 : (z == 1) ? W2 : (z == 2) ? W3 : W4;
    u16* WT        = (z == 0) ? T1 : (z == 1) ? T2 : (z == 2) ? T3 : T4;
    int K = (z == 0) ? 256 : 512;
    int k0 = by * 32;
    if (k0 >= K) return;
    int n0 = bx * 32;
    int tx = threadIdx.x & 31, ty = threadIdx.x >> 5;  // 32 x 8
    for (int i = 0; i < 32; i += 8)
        tile[ty + i][tx] = f2b(W[(size_t)(k0 + ty + i) * 512 + n0 + tx]);
    __syncthreads();
    for (int i = 0; i < 32; i += 8)
        WT[(size_t)(n0 + ty + i) * K + k0 + tx] = tile[tx][ty + i];
}

// Single block @1024 threads: dis = rsqrt(deg+1); exclusive scan -> off, cur.
// [R8 post-mortem: old 256-thr version ~30-40us (40 serial elems/thread on one
//  CU). 1024 thr -> 10 elems/thread.] Also zeroes the 4 work-steal counters.
__global__ void k_scan_all(const int* __restrict__ deg, float* __restrict__ dis,
                           int* __restrict__ off, int* __restrict__ cur,
                           int* __restrict__ ctr) {
    __shared__ int sd[N_NODES];    // 40 KB
    __shared__ int sums[1024];     // 4 KB
    int t = threadIdx.x;
    if (t < 4) ctr[t] = 0;
    for (int i = t; i < N_NODES; i += 1024) {
        int d = deg[i];
        sd[i] = d;
        dis[i] = rsqrtf((float)d + 1.0f);
    }
    __syncthreads();
    const int seg = (N_NODES + 1023) >> 10;  // 10
    int lo = t * seg, hi = lo + seg;
    if (lo > N_NODES) lo = N_NODES;
    if (hi > N_NODES) hi = N_NODES;
    int s = 0;
    for (int i = lo; i < hi; ++i) s += sd[i];
    sums[t] = s;
    __syncthreads();
    for (int d = 1; d < 1024; d <<= 1) {
        int v = (t >= d) ? sums[t - d] : 0;
        __syncthreads();
        sums[t] += v;
        __syncthreads();
    }
    int run = sums[t] - s;
    for (int i = lo; i < hi; ++i) {
        off[i] = run;
        cur[i] = run;
        run += sd[i];
    }
    if (t == 1023) off[N_NODES] = sums[1023];
}

// ---------------- fill CSR (by dst) ----------------------------------------------

__global__ void k_fill(const int* __restrict__ row, const int* __restrict__ col,
                       const float* __restrict__ dis, int* cur,
                       int* __restrict__ crow, float* __restrict__ cnorm) {
    int e = blockIdx.x * 256 + threadIdx.x;
    if (e < N_EDGES) {
        int r = row[e], c = col[e];
        int p = atomicAdd(&cur[c], 1);
        crow[p] = r;
        cnorm[p] = dis[r] * dis[c];
    }
}

// ---------------- CSR-gather aggregation, work-stealing ---------------------------
// Each wave steals one node at a time (atomicAdd counter) -> perfect load balance
// across degree variance + no round-quantization (grid 1024 blocks, all resident).
// CE bf16 elems per lane (C = CE*64). Self-loop fused. 8 gathers in flight,
// 4 chains, index prefetch.

template <int CE> struct VecT;
template <> struct VecT<4> { typedef us4 T; };
template <> struct VecT<8> { typedef us8 T; };

template <int CE>
__global__ void k_agg(const u16* __restrict__ in, u16* __restrict__ out,
                      const int* __restrict__ off, const int* __restrict__ crow,
                      const float* __restrict__ cnorm, const float* __restrict__ dis,
                      int* __restrict__ ctr) {
    typedef typename VecT<CE>::T VT;
    const int C = CE * 64;
    int lane = threadIdx.x & 63;
    int c = lane * CE;

    for (;;) {
        int my = 0;
        if (lane == 0) my = atomicAdd(ctr, 1);
        my = __shfl(my, 0);
        if (my >= N_NODES) return;
        int node = my;

        float d = dis[node];
        VT sv = *(const VT*)(in + (size_t)node * C + c);
        float a0[CE], a1[CE], a2[CE], a3[CE];
#pragma unroll
        for (int j = 0; j < CE; ++j) {
            a0[j] = b2f(sv[j]) * d * d;
            a1[j] = 0.f; a2[j] = 0.f; a3[j] = 0.f;
        }

        int i = off[node], hi = off[node + 1];
        int rA[8]; float nA[8];
        if (i + 8 <= hi) {
#pragma unroll
            for (int q = 0; q < 8; ++q) { rA[q] = crow[i + q]; nA[q] = cnorm[i + q]; }
        }
        while (i + 8 <= hi) {
            VT v[8];
#pragma unroll
            for (int q = 0; q < 8; ++q) v[q] = *(const VT*)(in + (size_t)rA[q] * C + c);
            int inext = i + 8;
            if (inext + 8 <= hi) {  // prefetch next batch's indices under gather latency
                int rB[8]; float nB[8];
#pragma unroll
                for (int q = 0; q < 8; ++q) { rB[q] = crow[inext + q]; nB[q] = cnorm[inext + q]; }
#pragma unroll
                for (int j = 0; j < CE; ++j) {
                    a0[j] = fmaf(b2f(v[0][j]), nA[0], a0[j]);
                    a1[j] = fmaf(b2f(v[1][j]), nA[1], a1[j]);
                    a2[j] = fmaf(b2f(v[2][j]), nA[2], a2[j]);
                    a3[j] = fmaf(b2f(v[3][j]), nA[3], a3[j]);
                }
#pragma unroll
                for (int j = 0; j < CE; ++j) {
                    a0[j] = fmaf(b2f(v[4][j]), nA[4], a0[j]);
                    a1[j] = fmaf(b2f(v[5][j]), nA[5], a1[j]);
                    a2[j] = fmaf(b2f(v[6][j]), nA[6], a2[j]);
                    a3[j] = fmaf(b2f(v[7][j]), nA[7], a3[j]);
                }
#pragma unroll
                for (int q = 0; q < 8; ++q) { rA[q] = rB[q]; nA[q] = nB[q]; }
            } else {
#pragma unroll
                for (int j = 0; j < CE; ++j) {
                    a0[j] = fmaf(b2f(v[0][j]), nA[0], a0[j]);
                    a1[j] = fmaf(b2f(v[1][j]), nA[1], a1[j]);
                    a2[j] = fmaf(b2f(v[2][j]), nA[2], a2[j]);
                    a3[j] = fmaf(b2f(v[3][j]), nA[3], a3[j]);
                }
#pragma unroll
                for (int j = 0; j < CE; ++j) {
                    a0[j] = fmaf(b2f(v[4][j]), nA[4], a0[j]);
                    a1[j] = fmaf(b2f(v[5][j]), nA[5], a1[j]);
                    a2[j] = fmaf(b2f(v[6][j]), nA[6], a2[j]);
                    a3[j] = fmaf(b2f(v[7][j]), nA[7], a3[j]);
                }
            }
            i = inext;
        }
        for (; i + 3 < hi; i += 4) {
            int r0 = crow[i], r1 = crow[i + 1], r2 = crow[i + 2], r3 = crow[i + 3];
            float n0 = cnorm[i], n1 = cnorm[i + 1], n2 = cnorm[i + 2], n3 = cnorm[i + 3];
            VT v0 = *(const VT*)(in + (size_t)r0 * C + c);
            VT v1 = *(const VT*)(in + (size_t)r1 * C + c);
            VT v2 = *(const VT*)(in + (size_t)r2 * C + c);
            VT v3 = *(const VT*)(in + (size_t)r3 * C + c);
#pragma unroll
            for (int j = 0; j < CE; ++j) {
                a0[j] = fmaf(b2f(v0[j]), n0, a0[j]);
                a1[j] = fmaf(b2f(v1[j]), n1, a1[j]);
                a2[j] = fmaf(b2f(v2[j]), n2, a2[j]);
                a3[j] = fmaf(b2f(v3[j]), n3, a3[j]);
            }
        }
        for (; i < hi; ++i) {
            int r0 = crow[i];
            float n0 = cnorm[i];
            VT v0 = *(const VT*)(in + (size_t)r0 * C + c);
#pragma unroll
            for (int j = 0; j < CE; ++j) a0[j] = fmaf(b2f(v0[j]), n0, a0[j]);
        }
        VT st;
#pragma unroll
        for (int j = 0; j < CE; ++j) st[j] = f2b((a0[j] + a1[j]) + (a2[j] + a3[j]));
        *(VT*)(out + (size_t)node * C + c) = st;
    }
}

// ---------------- 64x128-tile bf16 MFMA GEMM, double-buffered prefetch ------------
// [R7 structure. R8's counted-vmcnt variant measured neutral (+3.8us) -> reverted;
//  matches learn_hip m131-m141: implicit inter-block overlap already covers it.]
// A:[M,K] bf16, BT:[NO,K] bf16, bias f32. 4 waves 2x2, wave 32x64 (2x4 frags).
// BK=64 as two 32-k panels. Grid (4 n-tiles, 157 m-tiles) = 628 blocks.

static __device__ __forceinline__ void st_out(float* out, size_t idx, float v) { out[idx] = v; }
static __device__ __forceinline__ void st_out(u16* out, size_t idx, float v) { out[idx] = f2b(v); }

// 24 chunks of 16 rows x 32 k-elems (1KB each): 0..7 -> A, 8..23 -> B.
static __device__ __forceinline__ void gemm_stage(
        u16 (*Asb)[64][32], u16 (*Bsb)[128][32],
        const u16* const G[6], const int isA[6],
        const int P[6], const int R[6], int kk) {
#pragma unroll
    for (int q = 0; q < 6; ++q) {
        if (isA[q]) GLDS(G[q] + kk, &Asb[P[q]][R[q]][0]);
        else        GLDS(G[q] + kk, &Bsb[P[q]][R[q]][0]);
    }
}

static __device__ __forceinline__ void gemm_compute(
        const u16 (*Asb)[64][32], const u16 (*Bsb)[128][32],
        int wm, int wn, int l15, int kq, f32x4 acc[2][4]) {
#pragma unroll
    for (int p = 0; p < 2; ++p) {
        s16x8 a[2], bb[4];
#pragma unroll
        for (int mi = 0; mi < 2; ++mi)
            a[mi] = *(const s16x8*)&Asb[p][wm * 32 + mi * 16 + l15][kq * 8];
#pragma unroll
        for (int ni = 0; ni < 4; ++ni)
            bb[ni] = *(const s16x8*)&Bsb[p][wn * 64 + ni * 16 + l15][kq * 8];
#pragma unroll
        for (int mi = 0; mi < 2; ++mi)
#pragma unroll
            for (int ni = 0; ni < 4; ++ni)
                acc[mi][ni] = __builtin_amdgcn_mfma_f32_16x16x32_bf16(
                    a[mi], bb[ni], acc[mi][ni], 0, 0, 0);
    }
}

template <typename OT>
__global__ __launch_bounds__(256, 3) void k_gemm(
        const u16* __restrict__ A, const u16* __restrict__ BT,
        const float* __restrict__ bias, OT* __restrict__ out,
        int M, int K, int NO, int relu) {
    __shared__ u16 As[2][2][64][32];   // [buf][panel][m][k32]  16 KB
    __shared__ u16 Bs[2][2][128][32];  // [buf][panel][n][k32]  32 KB

    int tid = threadIdx.x;
    int w = tid >> 6;
    int lane = tid & 63;
    int wm = w >> 1, wn = w & 1;
    int n0 = blockIdx.x * 128;
    int m0 = blockIdx.y * 64;
    int l15 = lane & 15;
    int kq = lane >> 4;  // 0..3

    int srow = lane >> 2;        // 0..15 (row within 16-row chunk)
    int skc = (lane & 3) * 8;    // k elems within 32-panel

    const u16* G[6];
    int isA[6], P[6], R[6];
#pragma unroll
    for (int q = 0; q < 6; ++q) {
        int ch = w * 6 + q;  // 0..23
        if (ch < 8) {
            isA[q] = 1;
            P[q] = ch >> 2;
            R[q] = (ch & 3) * 16;
            int ar = m0 + R[q] + srow;
            if (ar > M - 1) ar = M - 1;
            G[q] = A + (size_t)ar * K + P[q] * 32 + skc;
        } else {
            int cb = ch - 8;
            isA[q] = 0;
            P[q] = cb >> 3;
            R[q] = (cb & 7) * 16;
            int br = n0 + R[q] + srow;  // NO=512 exact, no clamp
            G[q] = BT + (size_t)br * K + P[q] * 32 + skc;
        }
    }

    f32x4 acc[2][4];
#pragma unroll
    for (int mi = 0; mi < 2; ++mi)
#pragma unroll
        for (int ni = 0; ni < 4; ++ni) acc[mi][ni] = (f32x4){0.f, 0.f, 0.f, 0.f};

    int NT = K >> 6;  // 4 or 8, always even
    gemm_stage(As[0], Bs[0], G, isA, P, R, 0);
    __syncthreads();
    for (int t = 0; t < NT; t += 2) {
        gemm_stage(As[1], Bs[1], G, isA, P, R, (t + 1) * 64);
        gemm_compute(As[0], Bs[0], wm, wn, l15, kq, acc);
        __syncthreads();
        if (t + 2 < NT)
            gemm_stage(As[0], Bs[0], G, isA, P, R, (t + 2) * 64);
        gemm_compute(As[1], Bs[1], wm, wn, l15, kq, acc);
        __syncthreads();
    }

    // C/D layout: col = lane&15, row = (lane>>4)*4 + r   [m89-verified]
    int r0o = (lane >> 4) * 4;
    int cm = m0 + wm * 32;
    int cn = n0 + wn * 64;
    float bv[4];
#pragma unroll
    for (int ni = 0; ni < 4; ++ni) bv[ni] = bias[cn + ni * 16 + l15];
#pragma unroll
    for (int mi = 0; mi < 2; ++mi) {
#pragma unroll
        for (int r = 0; r < 4; ++r) {
            int rowa = cm + mi * 16 + r0o + r;
            if (rowa < M) {
#pragma unroll
                for (int ni = 0; ni < 4; ++ni) {
                    float v = acc[mi][ni][r] + bv[ni];
                    if (relu) v = fmaxf(v, 0.f);
                    st_out(out, (size_t)rowa * NO + cn + ni * 16 + l15, v);
                }
            }
        }
    }
}

// ---------------- launch ----------------

extern "C" void kernel_launch(void* const* d_in, const int* in_sizes, int n_in,
                              void* d_out, int out_size, void* d_ws, size_t ws_size,
                              hipStream_t stream) {
    const float* x  = (const float*)d_in[0];
    const int*   ei = (const int*)d_in[1];
    const float* W1 = (const float*)d_in[2];
    const float* b1 = (const float*)d_in[3];
    const float* W2 = (const float*)d_in[4];
    const float* b2 = (const float*)d_in[5];
    const float* W3 = (const float*)d_in[6];
    const float* b3 = (const float*)d_in[7];
    const float* W4 = (const float*)d_in[8];
    const float* b4 = (const float*)d_in[9];

    char* ws = (char*)d_ws;
    size_t o = 0;
    auto alloc = [&](size_t bytes) {
        char* p = ws + o;
        o = (o + bytes + 255) & ~(size_t)255;
        return p;
    };
    int*   row   = (int*)alloc(N_EDGES * 4);
    int*   col   = (int*)alloc(N_EDGES * 4);
    int*   deg   = (int*)alloc(N_NODES * 4);
    float* dis   = (float*)alloc(N_NODES * 4);
    int*   off   = (int*)alloc((N_NODES + 1) * 4);
    int*   cur   = (int*)alloc(N_NODES * 4);
    int*   crow  = (int*)alloc(N_EDGES * 4);
    float* cnorm = (float*)alloc(N_EDGES * 4);
    int*   ctr   = (int*)alloc(4 * 4);   // work-steal counters (zeroed in k_scan_all)
    u16*   WT1   = (u16*)alloc((size_t)512 * 256 * 2);
    u16*   WT2   = (u16*)alloc((size_t)512 * 512 * 2);
    u16*   WT3   = (u16*)alloc((size_t)512 * 512 * 2);
    u16*   WT4   = (u16*)alloc((size_t)512 * 512 * 2);
    u16*   xb    = (u16*)alloc((size_t)N_NODES * 256 * 2);  // bf16 x
    u16*   s     = (u16*)alloc((size_t)N_NODES * 512 * 2);  // bf16 aggregated
    u16*   h     = (u16*)alloc((size_t)N_NODES * 512 * 2);  // bf16 hidden
    float* outb  = (float*)d_out;

    dim3 b256(256);
    const dim3 gG(4, 157);  // 64x128 tiles -> 628 blocks
    const int  gA = 1024;   // work-stealing: all blocks resident, waves steal nodes

    hipMemsetAsync(deg, 0, N_NODES * 4, stream);
    k_prep<<<2500 + 1024, b256, 0, stream>>>(ei, x, xb, row, col, deg,
                                             W1, W2, W3, W4, WT1, WT2, WT3, WT4);
    k_scan_all<<<1, dim3(1024), 0, stream>>>(deg, dis, off, cur, ctr);
    k_fill<<<625, b256, 0, stream>>>(row, col, dis, cur, crow, cnorm);

    // Layer 1: s = bf16(A_norm @ x) [C=256], h = bf16(relu(s @ W1 + b1))
    k_agg<4><<<gA, b256, 0, stream>>>(xb, s, off, crow, cnorm, dis, ctr + 0);
    k_gemm<u16><<<gG, b256, 0, stream>>>(s, WT1, b1, h, N_NODES, 256, 512, 1);
    // Layer 2
    k_agg<8><<<gA, b256, 0, stream>>>(h, s, off, crow, cnorm, dis, ctr + 1);
    k_gemm<u16><<<gG, b256, 0, stream>>>(s, WT2, b2, h, N_NODES, 512, 512, 1);
    // Layer 3
    k_agg<8><<<gA, b256, 0, stream>>>(h, s, off, crow, cnorm, dis, ctr + 2);
    k_gemm<u16><<<gG, b256, 0, stream>>>(s, WT3, b3, h, N_NODES, 512, 512, 1);
    // Layer 4 (no relu) -> f32 d_out
    k_agg<8><<<gA, b256, 0, stream>>>(h, s, off, crow, cnorm, dis, ctr + 3);
    k_gemm<float><<<gG, b256, 0, stream>>>(s, WT4, b4, outb, N_NODES, 512, 512, 0);
}

// Round 11
// 250.360 us; speedup vs baseline: 3.5001x; 3.5001x over previous
//
#include <hip/hip_runtime.h>
#include <hip/hip_bf16.h>

#define N_NODES 10000
#define N_EDGES 160000

typedef __hip_bfloat16 bf16;
typedef unsigned short u16;
typedef float f32x4 __attribute__((ext_vector_type(4)));
typedef short s16x8 __attribute__((ext_vector_type(8)));
typedef unsigned short us8 __attribute__((ext_vector_type(8)));
typedef unsigned short us4 __attribute__((ext_vector_type(4)));

static __device__ __forceinline__ float b2f(u16 u) {
    unsigned v = (unsigned)u << 16;
    return __uint_as_float(v);
}
static __device__ __forceinline__ u16 f2b(float f) {
    bf16 b = __float2bfloat16(f);
    return *reinterpret_cast<u16*>(&b);
}

// async global->LDS, 16B per lane; LDS dest = wave-uniform base + lane*16
#define GLDS(gp, lp)                                                         \
    __builtin_amdgcn_global_load_lds(                                        \
        (const __attribute__((address_space(1))) void*)(const void*)(gp),    \
        (__attribute__((address_space(3))) void*)(lp), 16, 0, 0)

// ---------------- prep: x conv + edge extract + degree count + W transposes ------
// blocks [0,2500): xb convert + edge extract + deg count. deg pre-zeroed.
// blocks [2500, 2500+1024): transpose WT[n][k] = bf16(W[k][n]).

__global__ void k_prep(const int* __restrict__ ei, const float* __restrict__ x,
                       u16* __restrict__ xb,
                       int* __restrict__ row, int* __restrict__ col,
                       int* __restrict__ deg,
                       const float* __restrict__ W1, const float* __restrict__ W2,
                       const float* __restrict__ W3, const float* __restrict__ W4,
                       u16* __restrict__ T1, u16* __restrict__ T2,
                       u16* __restrict__ T3, u16* __restrict__ T4) {
    __shared__ u16 tile[32][33];
    if (blockIdx.x < 2500) {
        int t = blockIdx.x * 256 + threadIdx.x;  // 0 .. 639999
        float4 v = *(const float4*)(x + (size_t)t * 4);
        us4 st;
        st[0] = f2b(v.x); st[1] = f2b(v.y); st[2] = f2b(v.z); st[3] = f2b(v.w);
        *(us4*)(xb + (size_t)t * 4) = st;

        if (t < N_EDGES) {
            bool is64 = true;
#pragma unroll
            for (int k = 0; k < 8; ++k) is64 = is64 && (ei[2 * k + 1] == 0);
            int r, c;
            if (is64) {
                r = ei[2 * t];
                c = ei[2 * (N_EDGES + t)];
            } else {
                r = ei[t];
                c = ei[N_EDGES + t];
            }
            row[t] = r;
            col[t] = c;
            atomicAdd(&deg[c], 1);
        }
        return;
    }
    int b = blockIdx.x - 2500;        // 0..1023
    int z = b >> 8;                   // 0..3
    int rem = b & 255;
    int by = rem >> 4, bx = rem & 15;
    const float* W = (z == 0) ? W1 : (z == 1) ? W2 : (z == 2) ? W3 : W4;
    u16* WT        = (z == 0) ? T1 : (z == 1) ? T2 : (z == 2) ? T3 : T4;
    int K = (z == 0) ? 256 : 512;
    int k0 = by * 32;
    if (k0 >= K) return;
    int n0 = bx * 32;
    int tx = threadIdx.x & 31, ty = threadIdx.x >> 5;  // 32 x 8
    for (int i = 0; i < 32; i += 8)
        tile[ty + i][tx] = f2b(W[(size_t)(k0 + ty + i) * 512 + n0 + tx]);
    __syncthreads();
    for (int i = 0; i < 32; i += 8)
        WT[(size_t)(n0 + ty + i) * K + k0 + tx] = tile[tx][ty + i];
}

// Single block @1024 threads: dis = rsqrt(deg+1); exclusive scan -> off, cur.
// [256-thr version was ~30-40us serial on one CU; 1024 thr -> 10 elems/thread.]
__global__ void k_scan_all(const int* __restrict__ deg, float* __restrict__ dis,
                           int* __restrict__ off, int* __restrict__ cur) {
    __shared__ int sd[N_NODES];    // 40 KB
    __shared__ int sums[1024];     // 4 KB
    int t = threadIdx.x;
    for (int i = t; i < N_NODES; i += 1024) {
        int d = deg[i];
        sd[i] = d;
        dis[i] = rsqrtf((float)d + 1.0f);
    }
    __syncthreads();
    const int seg = (N_NODES + 1023) >> 10;  // 10
    int lo = t * seg, hi = lo + seg;
    if (lo > N_NODES) lo = N_NODES;
    if (hi > N_NODES) hi = N_NODES;
    int s = 0;
    for (int i = lo; i < hi; ++i) s += sd[i];
    sums[t] = s;
    __syncthreads();
    for (int d = 1; d < 1024; d <<= 1) {
        int v = (t >= d) ? sums[t - d] : 0;
        __syncthreads();
        sums[t] += v;
        __syncthreads();
    }
    int run = sums[t] - s;
    for (int i = lo; i < hi; ++i) {
        off[i] = run;
        cur[i] = run;
        run += sd[i];
    }
    if (t == 1023) off[N_NODES] = sums[1023];
}

// ---------------- fill CSR (by dst) ----------------------------------------------

__global__ void k_fill(const int* __restrict__ row, const int* __restrict__ col,
                       const float* __restrict__ dis, int* cur,
                       int* __restrict__ crow, float* __restrict__ cnorm) {
    int e = blockIdx.x * 256 + threadIdx.x;
    if (e < N_EDGES) {
        int r = row[e], c = col[e];
        int p = atomicAdd(&cur[c], 1);
        crow[p] = r;
        cnorm[p] = dis[r] * dis[c];
    }
}

// ---------------- CSR-gather aggregation, bf16 in/out, f32 accumulate -------------
// [R9 post-mortem: work-stealing for(;;) loop spilled the accumulator set to
//  scratch (WRITE_SIZE 10MB->199MB, 179us/dispatch). Static one-wave-per-node
//  body keeps all accumulators in VGPRs.]
// One wave per node; CE bf16 elems per lane (C = CE*64). Self-loop fused.
// 8 gathers in flight, 4 chains, index prefetch.

template <int CE> struct VecT;
template <> struct VecT<4> { typedef us4 T; };
template <> struct VecT<8> { typedef us8 T; };

template <int CE>
__global__ void k_agg(const u16* __restrict__ in, u16* __restrict__ out,
                      const int* __restrict__ off, const int* __restrict__ crow,
                      const float* __restrict__ cnorm, const float* __restrict__ dis) {
    typedef typename VecT<CE>::T VT;
    const int C = CE * 64;
    int node = blockIdx.x * 4 + (threadIdx.x >> 6);  // grid exact: 2500*4
    int lane = threadIdx.x & 63;
    int c = lane * CE;

    float d = dis[node];
    VT sv = *(const VT*)(in + (size_t)node * C + c);
    float a0[CE], a1[CE], a2[CE], a3[CE];
#pragma unroll
    for (int j = 0; j < CE; ++j) {
        a0[j] = b2f(sv[j]) * d * d;
        a1[j] = 0.f; a2[j] = 0.f; a3[j] = 0.f;
    }

    int i = off[node], hi = off[node + 1];
    int rA[8]; float nA[8];
    if (i + 8 <= hi) {
#pragma unroll
        for (int q = 0; q < 8; ++q) { rA[q] = crow[i + q]; nA[q] = cnorm[i + q]; }
    }
    while (i + 8 <= hi) {
        VT v[8];
#pragma unroll
        for (int q = 0; q < 8; ++q) v[q] = *(const VT*)(in + (size_t)rA[q] * C + c);
        int inext = i + 8;
        if (inext + 8 <= hi) {  // prefetch next batch's indices under gather latency
            int rB[8]; float nB[8];
#pragma unroll
            for (int q = 0; q < 8; ++q) { rB[q] = crow[inext + q]; nB[q] = cnorm[inext + q]; }
#pragma unroll
            for (int j = 0; j < CE; ++j) {
                a0[j] = fmaf(b2f(v[0][j]), nA[0], a0[j]);
                a1[j] = fmaf(b2f(v[1][j]), nA[1], a1[j]);
                a2[j] = fmaf(b2f(v[2][j]), nA[2], a2[j]);
                a3[j] = fmaf(b2f(v[3][j]), nA[3], a3[j]);
            }
#pragma unroll
            for (int j = 0; j < CE; ++j) {
                a0[j] = fmaf(b2f(v[4][j]), nA[4], a0[j]);
                a1[j] = fmaf(b2f(v[5][j]), nA[5], a1[j]);
                a2[j] = fmaf(b2f(v[6][j]), nA[6], a2[j]);
                a3[j] = fmaf(b2f(v[7][j]), nA[7], a3[j]);
            }
#pragma unroll
            for (int q = 0; q < 8; ++q) { rA[q] = rB[q]; nA[q] = nB[q]; }
        } else {
#pragma unroll
            for (int j = 0; j < CE; ++j) {
                a0[j] = fmaf(b2f(v[0][j]), nA[0], a0[j]);
                a1[j] = fmaf(b2f(v[1][j]), nA[1], a1[j]);
                a2[j] = fmaf(b2f(v[2][j]), nA[2], a2[j]);
                a3[j] = fmaf(b2f(v[3][j]), nA[3], a3[j]);
            }
#pragma unroll
            for (int j = 0; j < CE; ++j) {
                a0[j] = fmaf(b2f(v[4][j]), nA[4], a0[j]);
                a1[j] = fmaf(b2f(v[5][j]), nA[5], a1[j]);
                a2[j] = fmaf(b2f(v[6][j]), nA[6], a2[j]);
                a3[j] = fmaf(b2f(v[7][j]), nA[7], a3[j]);
            }
        }
        i = inext;
    }
    for (; i + 3 < hi; i += 4) {
        int r0 = crow[i], r1 = crow[i + 1], r2 = crow[i + 2], r3 = crow[i + 3];
        float n0 = cnorm[i], n1 = cnorm[i + 1], n2 = cnorm[i + 2], n3 = cnorm[i + 3];
        VT v0 = *(const VT*)(in + (size_t)r0 * C + c);
        VT v1 = *(const VT*)(in + (size_t)r1 * C + c);
        VT v2 = *(const VT*)(in + (size_t)r2 * C + c);
        VT v3 = *(const VT*)(in + (size_t)r3 * C + c);
#pragma unroll
        for (int j = 0; j < CE; ++j) {
            a0[j] = fmaf(b2f(v0[j]), n0, a0[j]);
            a1[j] = fmaf(b2f(v1[j]), n1, a1[j]);
            a2[j] = fmaf(b2f(v2[j]), n2, a2[j]);
            a3[j] = fmaf(b2f(v3[j]), n3, a3[j]);
        }
    }
    for (; i < hi; ++i) {
        int r0 = crow[i];
        float n0 = cnorm[i];
        VT v0 = *(const VT*)(in + (size_t)r0 * C + c);
#pragma unroll
        for (int j = 0; j < CE; ++j) a0[j] = fmaf(b2f(v0[j]), n0, a0[j]);
    }
    VT st;
#pragma unroll
    for (int j = 0; j < CE; ++j) st[j] = f2b((a0[j] + a1[j]) + (a2[j] + a3[j]));
    *(VT*)(out + (size_t)node * C + c) = st;
}

// ---------------- 64x128-tile bf16 MFMA GEMM, double-buffered prefetch ------------
// [R7 structure, measured best. R8 counted-vmcnt neutral; R6 register-B-stream 3x
//  worse. B via coalesced global_load_lds.]
// A:[M,K] bf16, BT:[NO,K] bf16, bias f32. 4 waves 2x2, wave 32x64 (2x4 frags).
// BK=64 as two 32-k panels. Grid (4 n-tiles, 157 m-tiles) = 628 blocks.

static __device__ __forceinline__ void st_out(float* out, size_t idx, float v) { out[idx] = v; }
static __device__ __forceinline__ void st_out(u16* out, size_t idx, float v) { out[idx] = f2b(v); }

// 24 chunks of 16 rows x 32 k-elems (1KB each): 0..7 -> A, 8..23 -> B.
static __device__ __forceinline__ void gemm_stage(
        u16 (*Asb)[64][32], u16 (*Bsb)[128][32],
        const u16* const G[6], const int isA[6],
        const int P[6], const int R[6], int kk) {
#pragma unroll
    for (int q = 0; q < 6; ++q) {
        if (isA[q]) GLDS(G[q] + kk, &Asb[P[q]][R[q]][0]);
        else        GLDS(G[q] + kk, &Bsb[P[q]][R[q]][0]);
    }
}

static __device__ __forceinline__ void gemm_compute(
        const u16 (*Asb)[64][32], const u16 (*Bsb)[128][32],
        int wm, int wn, int l15, int kq, f32x4 acc[2][4]) {
#pragma unroll
    for (int p = 0; p < 2; ++p) {
        s16x8 a[2], bb[4];
#pragma unroll
        for (int mi = 0; mi < 2; ++mi)
            a[mi] = *(const s16x8*)&Asb[p][wm * 32 + mi * 16 + l15][kq * 8];
#pragma unroll
        for (int ni = 0; ni < 4; ++ni)
            bb[ni] = *(const s16x8*)&Bsb[p][wn * 64 + ni * 16 + l15][kq * 8];
#pragma unroll
        for (int mi = 0; mi < 2; ++mi)
#pragma unroll
            for (int ni = 0; ni < 4; ++ni)
                acc[mi][ni] = __builtin_amdgcn_mfma_f32_16x16x32_bf16(
                    a[mi], bb[ni], acc[mi][ni], 0, 0, 0);
    }
}

template <typename OT>
__global__ __launch_bounds__(256, 3) void k_gemm(
        const u16* __restrict__ A, const u16* __restrict__ BT,
        const float* __restrict__ bias, OT* __restrict__ out,
        int M, int K, int NO, int relu) {
    __shared__ u16 As[2][2][64][32];   // [buf][panel][m][k32]  16 KB
    __shared__ u16 Bs[2][2][128][32];  // [buf][panel][n][k32]  32 KB

    int tid = threadIdx.x;
    int w = tid >> 6;
    int lane = tid & 63;
    int wm = w >> 1, wn = w & 1;
    int n0 = blockIdx.x * 128;
    int m0 = blockIdx.y * 64;
    int l15 = lane & 15;
    int kq = lane >> 4;  // 0..3

    int srow = lane >> 2;        // 0..15 (row within 16-row chunk)
    int skc = (lane & 3) * 8;    // k elems within 32-panel

    const u16* G[6];
    int isA[6], P[6], R[6];
#pragma unroll
    for (int q = 0; q < 6; ++q) {
        int ch = w * 6 + q;  // 0..23
        if (ch < 8) {
            isA[q] = 1;
            P[q] = ch >> 2;
            R[q] = (ch & 3) * 16;
            int ar = m0 + R[q] + srow;
            if (ar > M - 1) ar = M - 1;
            G[q] = A + (size_t)ar * K + P[q] * 32 + skc;
        } else {
            int cb = ch - 8;
            isA[q] = 0;
            P[q] = cb >> 3;
            R[q] = (cb & 7) * 16;
            int br = n0 + R[q] + srow;  // NO=512 exact, no clamp
            G[q] = BT + (size_t)br * K + P[q] * 32 + skc;
        }
    }

    f32x4 acc[2][4];
#pragma unroll
    for (int mi = 0; mi < 2; ++mi)
#pragma unroll
        for (int ni = 0; ni < 4; ++ni) acc[mi][ni] = (f32x4){0.f, 0.f, 0.f, 0.f};

    int NT = K >> 6;  // 4 or 8, always even
    gemm_stage(As[0], Bs[0], G, isA, P, R, 0);
    __syncthreads();
    for (int t = 0; t < NT; t += 2) {
        gemm_stage(As[1], Bs[1], G, isA, P, R, (t + 1) * 64);
        gemm_compute(As[0], Bs[0], wm, wn, l15, kq, acc);
        __syncthreads();
        if (t + 2 < NT)
            gemm_stage(As[0], Bs[0], G, isA, P, R, (t + 2) * 64);
        gemm_compute(As[1], Bs[1], wm, wn, l15, kq, acc);
        __syncthreads();
    }

    // C/D layout: col = lane&15, row = (lane>>4)*4 + r   [m89-verified]
    int r0o = (lane >> 4) * 4;
    int cm = m0 + wm * 32;
    int cn = n0 + wn * 64;
    float bv[4];
#pragma unroll
    for (int ni = 0; ni < 4; ++ni) bv[ni] = bias[cn + ni * 16 + l15];
#pragma unroll
    for (int mi = 0; mi < 2; ++mi) {
#pragma unroll
        for (int r = 0; r < 4; ++r) {
            int rowa = cm + mi * 16 + r0o + r;
            if (rowa < M) {
#pragma unroll
                for (int ni = 0; ni < 4; ++ni) {
                    float v = acc[mi][ni][r] + bv[ni];
                    if (relu) v = fmaxf(v, 0.f);
                    st_out(out, (size_t)rowa * NO + cn + ni * 16 + l15, v);
                }
            }
        }
    }
}

// ---------------- launch ----------------

extern "C" void kernel_launch(void* const* d_in, const int* in_sizes, int n_in,
                              void* d_out, int out_size, void* d_ws, size_t ws_size,
                              hipStream_t stream) {
    const float* x  = (const float*)d_in[0];
    const int*   ei = (const int*)d_in[1];
    const float* W1 = (const float*)d_in[2];
    const float* b1 = (const float*)d_in[3];
    const float* W2 = (const float*)d_in[4];
    const float* b2 = (const float*)d_in[5];
    const float* W3 = (const float*)d_in[6];
    const float* b3 = (const float*)d_in[7];
    const float* W4 = (const float*)d_in[8];
    const float* b4 = (const float*)d_in[9];

    char* ws = (char*)d_ws;
    size_t o = 0;
    auto alloc = [&](size_t bytes) {
        char* p = ws + o;
        o = (o + bytes + 255) & ~(size_t)255;
        return p;
    };
    int*   row   = (int*)alloc(N_EDGES * 4);
    int*   col   = (int*)alloc(N_EDGES * 4);
    int*   deg   = (int*)alloc(N_NODES * 4);
    float* dis   = (float*)alloc(N_NODES * 4);
    int*   off   = (int*)alloc((N_NODES + 1) * 4);
    int*   cur   = (int*)alloc(N_NODES * 4);
    int*   crow  = (int*)alloc(N_EDGES * 4);
    float* cnorm = (float*)alloc(N_EDGES * 4);
    u16*   WT1   = (u16*)alloc((size_t)512 * 256 * 2);
    u16*   WT2   = (u16*)alloc((size_t)512 * 512 * 2);
    u16*   WT3   = (u16*)alloc((size_t)512 * 512 * 2);
    u16*   WT4   = (u16*)alloc((size_t)512 * 512 * 2);
    u16*   xb    = (u16*)alloc((size_t)N_NODES * 256 * 2);  // bf16 x
    u16*   s     = (u16*)alloc((size_t)N_NODES * 512 * 2);  // bf16 aggregated
    u16*   h     = (u16*)alloc((size_t)N_NODES * 512 * 2);  // bf16 hidden
    float* outb  = (float*)d_out;

    dim3 b256(256);
    const dim3 gG(4, 157);  // 64x128 tiles -> 628 blocks
    const int  gA = (N_NODES + 3) / 4;  // 2500: one wave/node

    hipMemsetAsync(deg, 0, N_NODES * 4, stream);
    k_prep<<<2500 + 1024, b256, 0, stream>>>(ei, x, xb, row, col, deg,
                                             W1, W2, W3, W4, WT1, WT2, WT3, WT4);
    k_scan_all<<<1, dim3(1024), 0, stream>>>(deg, dis, off, cur);
    k_fill<<<625, b256, 0, stream>>>(row, col, dis, cur, crow, cnorm);

    // Layer 1: s = bf16(A_norm @ x) [C=256], h = bf16(relu(s @ W1 + b1))
    k_agg<4><<<gA, b256, 0, stream>>>(xb, s, off, crow, cnorm, dis);
    k_gemm<u16><<<gG, b256, 0, stream>>>(s, WT1, b1, h, N_NODES, 256, 512, 1);
    // Layer 2
    k_agg<8><<<gA, b256, 0, stream>>>(h, s, off, crow, cnorm, dis);
    k_gemm<u16><<<gG, b256, 0, stream>>>(s, WT2, b2, h, N_NODES, 512, 512, 1);
    // Layer 3
    k_agg<8><<<gA, b256, 0, stream>>>(h, s, off, crow, cnorm, dis);
    k_gemm<u16><<<gG, b256, 0, stream>>>(s, WT3, b3, h, N_NODES, 512, 512, 1);
    // Layer 4 (no relu) -> f32 d_out
    k_agg<8><<<gA, b256, 0, stream>>>(h, s, off, crow, cnorm, dis);
    k_gemm<float><<<gG, b256, 0, stream>>>(s, WT4, b4, outb, N_NODES, 512, 512, 0);
}